// Round 7
// baseline (609.342 us; speedup 1.0000x reference)
//
#include <hip/hip_runtime.h>
#include <hip/hip_bf16.h>
#include <math.h>

// GRACE-style graph contrastive loss, MI355X (gfx950).
// R7: gram3 epilogue muls eliminated via sqrt(KE) input pre-scale (bilinear dot);
// feat fp32->bf16 cvt folded into setup_k (gemm1 -> plain bf16 path, was 1-wave/SIMD
// VALU-bound on inline cvt); reduceS+loss fused (rloss_k). gram3 launch_bounds(256,8).
// R6 post-mortem: gram3 is VALU-issue-bound (instruction census ~1100cyc/wave matches
// 55us); tail outside gram3 ~245us dominated by gemm1/gathers/launches.

#define NROWS 8192
#define MROWS 16384
#define NEDGE 262144

typedef __attribute__((ext_vector_type(8))) short bf16x8;
typedef __attribute__((ext_vector_type(4))) float f32x4;
typedef __attribute__((ext_vector_type(2))) float f32x2;
typedef long long i64;

__device__ __forceinline__ short f2bf(float f){
  union { float f; unsigned u; } cv; cv.f = f;
  unsigned u = cv.u;
  unsigned r = (u + 0x7fffu + ((u >> 16) & 1u)) >> 16;  // RNE; inputs finite
  return (short)r;
}
__device__ __forceinline__ f32x4 mfma16(bf16x8 a, bf16x8 b, f32x4 c){
  return __builtin_amdgcn_mfma_f32_16x16x32_bf16(a, b, c, 0, 0, 0);
}
__device__ __forceinline__ float fexp2(float x){
#if __has_builtin(__builtin_amdgcn_exp2f)
  return __builtin_amdgcn_exp2f(x);   // raw v_exp_f32; args bounded |x|<3
#else
  return exp2f(x);
#endif
}

// ---- fp8 e4m3fn pack (RNE) ----
__device__ unsigned char f2e4m3_sw(float f){
  float a = fabsf(f);
  unsigned s = (__float_as_uint(f)>>24)&0x80u;
  if (!(a>0.f)) return (unsigned char)s;
  if (a>448.f) a=448.f;
  int e; frexpf(a,&e);
  int eff=e-1;
  unsigned code;
  if (eff<-6){
    float q=rintf(a*512.f);
    code=(unsigned)q; if(code>7)code=7;
  } else {
    float q=rintf(a*exp2f((float)(3-eff)));
    unsigned mant=(unsigned)q;
    if(mant>=16){mant=8;eff++;}
    if(eff>8) return (unsigned char)(s|0x7e);
    code=((unsigned)(eff+7)<<3)|(mant-8);
  }
  return (unsigned char)(s|code);
}
__device__ __forceinline__ unsigned short pack2fp8(float a, float b){
#if __has_builtin(__builtin_amdgcn_cvt_pk_fp8_f32)
  int v = __builtin_amdgcn_cvt_pk_fp8_f32(a, b, 0, false);
  return (unsigned short)(v & 0xffff);
#else
  return (unsigned short)((unsigned)f2e4m3_sw(a) | ((unsigned)f2e4m3_sw(b)<<8));
#endif
}

// ---- fused setup: weight transpose+bf16 | degree histogram | feat fp32->bf16 ----
struct WtArgs {
  const float* src[6];
  short* dst[6];
  int K[6], N[6];
  int off[7];
  int nwt;
};
__global__ void setup_k(WtArgs a, const int* __restrict__ ei1, const int* __restrict__ ei2,
                        int* __restrict__ deg1, int* __restrict__ deg2,
                        const float* __restrict__ feat1, const float* __restrict__ feat2,
                        short* __restrict__ fb){
  int b = blockIdx.x;
  if (b < a.nwt){
    int i = b*256 + threadIdx.x;
    if (i >= a.off[6]) return;
    int s = 0;
    #pragma unroll
    for (int j=1;j<6;j++) if (i >= a.off[j]) s=j;
    int l = i - a.off[s];
    int K=a.K[s], N=a.N[s];
    int k=l/N, n=l-k*N;
    a.dst[s][(long)n*K+k] = f2bf(a.src[s][l]);
  } else if (b < a.nwt + 2*(NEDGE/256)){
    int hb = b - a.nwt;
    const int* ei = (hb < NEDGE/256) ? ei1 : ei2;
    int* deg = (hb < NEDGE/256) ? deg1 : deg2;
    int e = (hb % (NEDGE/256))*256 + threadIdx.x;
    atomicAdd(&deg[ei[e]], 1);
  } else {
    // feat cvt: 8192 blocks, one float4 per thread over [feat1;feat2] -> fb bf16
    int idx = (b - a.nwt - 2*(NEDGE/256))*256 + threadIdx.x;   // float4 idx, 0..2097151
    int row = idx >> 7, c4 = idx & 127;
    const float* src = (row < NROWS) ? (feat1 + (long)row*512 + c4*4)
                                     : (feat2 + (long)(row-NROWS)*512 + c4*4);
    float4 f = *(const float4*)src;
    uint2 o;
    o.x = (unsigned)(unsigned short)f2bf(f.x) | ((unsigned)(unsigned short)f2bf(f.y)<<16);
    o.y = (unsigned)(unsigned short)f2bf(f.z) | ((unsigned)(unsigned short)f2bf(f.w)<<16);
    *(uint2*)(fb + (long)row*512 + c4*4) = o;
  }
}

// ---- generic tall-skinny MFMA GEMM: Out[M,NN] = act(A[M,KK] @ Bt[NN,KK]^T + bias) ----
template<int NN, int KK, int ACT, bool BIAS, bool OUTF32>
__global__ __launch_bounds__(256) void gemm_k(const void* __restrict__ A0,
                                              const short* __restrict__ Bt, const float* __restrict__ bias,
                                              void* __restrict__ Out){
  constexpr int WM = (NN >= 64) ? 64 : 16;
  constexpr int WN = (NN >= 64) ? (NN/4) : NN;
  constexpr int MT = WM/16, NT = WN/16;
  const int tid = threadIdx.x;
  const int wave = tid >> 6, lane = tid & 63, quad = lane >> 4, cl = lane & 15;
  const int m0 = blockIdx.x * 64;
  const int wmo = (NN >= 64) ? 0 : wave*16;
  const int wno = (NN >= 64) ? wave*WN : 0;

  f32x4 zero = {0.f,0.f,0.f,0.f};
  f32x4 acc[MT][NT];
  #pragma unroll
  for (int i=0;i<MT;i++)
    #pragma unroll
    for (int j=0;j<NT;j++) acc[i][j] = zero;

  #pragma unroll
  for (int kc = 0; kc < KK/32; kc++){
    const int ko = kc*32 + quad*8;
    bf16x8 a[MT], b[NT];
    #pragma unroll
    for (int mt=0; mt<MT; mt++){
      int row = m0 + wmo + mt*16 + cl;
      a[mt] = *(const bf16x8*)((const short*)A0 + (long)row*KK + ko);
    }
    #pragma unroll
    for (int nt=0; nt<NT; nt++)
      b[nt] = *(const bf16x8*)(Bt + (long)(wno + nt*16 + cl)*KK + ko);
    #pragma unroll
    for (int mt=0; mt<MT; mt++)
      #pragma unroll
      for (int nt=0; nt<NT; nt++)
        acc[mt][nt] = mfma16(a[mt], b[nt], acc[mt][nt]);
  }
  #pragma unroll
  for (int mt=0; mt<MT; mt++){
    #pragma unroll
    for (int nt=0; nt<NT; nt++){
      int col = wno + nt*16 + cl;
      float bv = 0.f;
      if constexpr (BIAS) bv = bias[col];
      #pragma unroll
      for (int r=0;r<4;r++){
        int row = m0 + wmo + mt*16 + quad*4 + r;
        float v = acc[mt][nt][r] + bv;
        if (ACT==1) v = fmaxf(v, 0.f);
        if (ACT==2) v = (v > 0.f) ? v : expm1f(v);
        if constexpr (OUTF32) ((float*)Out)[(long)row*NN + col] = v;
        else ((short*)Out)[(long)row*NN + col] = f2bf(v);
      }
    }
  }
}

// ---- CSR build (both graphs fused per kernel) ----
__global__ void scan2_k(const int* __restrict__ deg1, int* __restrict__ rs1, int* __restrict__ cur1,
                        const int* __restrict__ deg2, int* __restrict__ rs2, int* __restrict__ cur2){
  const int* deg = blockIdx.x ? deg2 : deg1;
  int* rowstart = blockIdx.x ? rs2 : rs1;
  int* cursor = blockIdx.x ? cur2 : cur1;
  __shared__ int csum[256];
  __shared__ int base[257];
  int t = threadIdx.x;
  int loc[32];
  int s = 0;
  for (int j=0;j<32;j++){ int d = deg[t*32+j]; loc[j] = s; s += d; }
  csum[t] = s;
  __syncthreads();
  if (t==0){ int a=0; for (int i=0;i<256;i++){ base[i]=a; a+=csum[i]; } base[256]=a; }
  __syncthreads();
  for (int j=0;j<32;j++){ int v = base[t] + loc[j]; rowstart[t*32+j]=v; cursor[t*32+j]=v; }
  if (t==0) rowstart[NROWS] = base[256];
}
__global__ void fill2_k(const int* __restrict__ ei1, const float* __restrict__ w1, int* __restrict__ cur1,
                        int* __restrict__ ecol1, float* __restrict__ ew1,
                        const int* __restrict__ ei2, const float* __restrict__ w2, int* __restrict__ cur2,
                        int* __restrict__ ecol2, float* __restrict__ ew2){
  int b = blockIdx.x;
  bool g2 = (b >= NEDGE/256);
  const int* ei = g2 ? ei2 : ei1;
  const float* w = g2 ? w2 : w1;
  int* cursor = g2 ? cur2 : cur1;
  int* ecol = g2 ? ecol2 : ecol1;
  float* ew = g2 ? ew2 : ew1;
  int e = (b % (NEDGE/256))*256 + threadIdx.x;
  int r = ei[e];
  int p = atomicAdd(&cursor[r], 1);
  ecol[p] = ei[NEDGE + e];
  ew[p] = w[e];
}

// ---- GCN aggregation (gather form), latency-optimized: 8 gathers in flight ----
__device__ __forceinline__ void acc8(float* acc, int4 v, float f){
  const unsigned* u = (const unsigned*)&v;
  #pragma unroll
  for (int i=0;i<4;i++){
    union{unsigned x; float y;} lo, hi;
    lo.x = u[i] << 16;
    hi.x = u[i] & 0xffff0000u;
    acc[2*i]   = fmaf(f, lo.y, acc[2*i]);
    acc[2*i+1] = fmaf(f, hi.y, acc[2*i+1]);
  }
}

template<int C, bool RELU, bool HASB>
__global__ __launch_bounds__(256) void gather_k(const short* __restrict__ sup,
    const int* __restrict__ rs1, const int* __restrict__ ec1, const float* __restrict__ w1,
    const int* __restrict__ rs2, const int* __restrict__ ec2, const float* __restrict__ w2,
    const float* __restrict__ bias, short* __restrict__ out){
  constexpr int G = C/8;
  const int g = threadIdx.x % G;
  const int sub = threadIdx.x / G;
  const int row = blockIdx.x*(256/G) + sub;
  const int* rs; const int* ec; const float* w; int soff, lr;
  if (row < NROWS){ rs=rs1; ec=ec1; w=w1; soff=0; lr=row; }
  else            { rs=rs2; ec=ec2; w=w2; soff=NROWS; lr=row-NROWS; }
  const short* sb = sup + (long)soff*C + g*8;
  float acc[8];
  #pragma unroll
  for (int j=0;j<8;j++) acc[j] = HASB ? bias[g*8+j] : 0.f;
  const int s = rs[lr], e = rs[lr+1];
  int k = s;
  for (; k+8 <= e; k+=8){
    int c0=ec[k],c1=ec[k+1],c2=ec[k+2],c3=ec[k+3],c4=ec[k+4],c5=ec[k+5],c6=ec[k+6],c7=ec[k+7];
    float f0=w[k],f1=w[k+1],f2=w[k+2],f3=w[k+3],f4=w[k+4],f5=w[k+5],f6=w[k+6],f7=w[k+7];
    int4 v0 = *(const int4*)(sb + (long)c0*C);
    int4 v1 = *(const int4*)(sb + (long)c1*C);
    int4 v2 = *(const int4*)(sb + (long)c2*C);
    int4 v3 = *(const int4*)(sb + (long)c3*C);
    int4 v4 = *(const int4*)(sb + (long)c4*C);
    int4 v5 = *(const int4*)(sb + (long)c5*C);
    int4 v6 = *(const int4*)(sb + (long)c6*C);
    int4 v7 = *(const int4*)(sb + (long)c7*C);
    acc8(acc,v0,f0); acc8(acc,v1,f1); acc8(acc,v2,f2); acc8(acc,v3,f3);
    acc8(acc,v4,f4); acc8(acc,v5,f5); acc8(acc,v6,f6); acc8(acc,v7,f7);
  }
  for (; k+4 <= e; k+=4){
    int c0=ec[k],c1=ec[k+1],c2=ec[k+2],c3=ec[k+3];
    float f0=w[k],f1=w[k+1],f2=w[k+2],f3=w[k+3];
    int4 v0 = *(const int4*)(sb + (long)c0*C);
    int4 v1 = *(const int4*)(sb + (long)c1*C);
    int4 v2 = *(const int4*)(sb + (long)c2*C);
    int4 v3 = *(const int4*)(sb + (long)c3*C);
    acc8(acc,v0,f0); acc8(acc,v1,f1); acc8(acc,v2,f2); acc8(acc,v3,f3);
  }
  for (; k < e; k++){
    int c0=ec[k]; float f0=w[k];
    int4 v0 = *(const int4*)(sb + (long)c0*C);
    acc8(acc,v0,f0);
  }
  int4 ov;
  unsigned* ou = (unsigned*)&ov;
  #pragma unroll
  for (int i=0;i<4;i++){
    float a0 = acc[2*i], a1 = acc[2*i+1];
    if (RELU){ a0 = fmaxf(a0,0.f); a1 = fmaxf(a1,0.f); }
    unsigned p0 = (unsigned)(unsigned short)f2bf(a0);
    unsigned p1 = (unsigned)(unsigned short)f2bf(a1);
    ou[i] = p0 | (p1<<16);
  }
  *(int4*)(out + (long)row*C + g*8) = ov;
}

// ---- normalize rows of z (fp32 [16384,128]) -> fp8 * sqrt(KE) in MFMA fragment
// order (Zf); bdot[i] = z1n_i . z2n_i (fp32, unscaled). The sqrt(KE) pre-scale makes
// the Gram MFMA produce KE*(zi.zj) directly (bilinear), killing the epilogue mul.
__global__ __launch_bounds__(256) void norm_k(const float* __restrict__ z, unsigned short* __restrict__ Zf,
                                              float* __restrict__ bdot){
  const float SQKE = 1.6986436f;   // sqrt(2*log2(e))
  int wave = threadIdx.x>>6, lane = threadIdx.x&63;
  int i = blockIdx.x*4 + wave;   // row pair (i, i+8192)
  float2 a2 = *(const float2*)(z + (long)i*128 + lane*2);
  float2 b2 = *(const float2*)(z + (long)(i+NROWS)*128 + lane*2);
  float sa = a2.x*a2.x + a2.y*a2.y;
  float sb = b2.x*b2.x + b2.y*b2.y;
  #pragma unroll
  for (int m=1;m<64;m<<=1){ sa += __shfl_xor(sa,m); sb += __shfl_xor(sb,m); }
  float ra = 1.f / fmaxf(sqrtf(sa), 1e-12f);
  float rb = 1.f / fmaxf(sqrtf(sb), 1e-12f);
  float ras = ra*SQKE, rbs = rb*SQKE;
  const int d = lane>>1, kc = d>>3, q = (d>>1)&3, j4 = d&1, h = lane&1;
  const int base = kc*128 + j4;
  {
    int r = i;
    long o = ((long)(r>>4)*512 + base + ((r&15)+16*q)*2)*2 + h;
    Zf[o] = pack2fp8(a2.x*ras, a2.y*ras);
  }
  {
    int r = i + NROWS;
    long o = ((long)(r>>4)*512 + base + ((r&15)+16*q)*2)*2 + h;
    Zf[o] = pack2fp8(b2.x*rbs, b2.y*rbs);
  }
  float dd = (a2.x*ra)*(b2.x*rb) + (a2.y*ra)*(b2.y*rb);
  #pragma unroll
  for (int m=1;m<64;m<<=1) dd += __shfl_xor(dd,m);
  if (lane==0) bdot[i] = dd;
}

// ---- LDS-free symmetric exp-Gram partials. One 64x64 tile per WAVE over the upper
// triangle of the 256x256 tile grid. Inputs pre-scaled by sqrt(KE): epilogue is raw exp2.
__global__ __launch_bounds__(256,8) void gram3_k(const unsigned char* __restrict__ Zf,
                                                 float* __restrict__ P){
  __shared__ float srow[4][64];
  __shared__ float scol[4][64];
  const int wave = threadIdx.x>>6, lane = threadIdx.x&63;
  const int t = blockIdx.x*4 + wave;           // UT tile index, T=256
  int ti = (int)((513.0f - sqrtf(513.0f*513.0f - 8.0f*(float)t))*0.5f);
  while ((ti+1)*256 - ((ti+1)*ti)/2 <= t) ti++;
  while (ti*256 - (ti*(ti-1))/2 > t) ti--;
  const int tj = ti + (t - (ti*256 - (ti*(ti-1))/2));
  const unsigned char* za = Zf + (long)ti*16*512 + lane*8;
  const unsigned char* zb = Zf + (long)tj*16*512 + lane*8;

  f32x4 zero = {0.f,0.f,0.f,0.f};
  f32x4 acc[4][4];
  #pragma unroll
  for (int i=0;i<4;i++)
    #pragma unroll
    for (int j=0;j<4;j++) acc[i][j]=zero;

  i64 aA[4], bA[4], aB[4], bB[4];
  #pragma unroll
  for (int x=0;x<4;x++){
    aA[x] = *(const i64*)(za + (x*4+0)*512);
    bA[x] = *(const i64*)(zb + (x*4+0)*512);
  }
  #pragma unroll
  for (int kc=0;kc<4;kc++){
    i64* ac = (kc&1) ? aB : aA;
    i64* bc = (kc&1) ? bB : bA;
    i64* an = (kc&1) ? aA : aB;
    i64* bn = (kc&1) ? bA : bB;
    if (kc<3){
      #pragma unroll
      for (int x=0;x<4;x++){
        an[x] = *(const i64*)(za + (x*4+kc+1)*512);
        bn[x] = *(const i64*)(zb + (x*4+kc+1)*512);
      }
    }
    #pragma unroll
    for (int mt=0;mt<4;mt++)
      #pragma unroll
      for (int nt=0;nt<4;nt++)
        acc[mt][nt] = __builtin_amdgcn_mfma_f32_16x16x32_fp8_fp8(ac[mt], bc[nt], acc[mt][nt], 0, 0, 0);
  }

  const int quad = lane>>4, cl = lane&15;
  f32x2 z2 = {0.f,0.f};
  f32x2 rs01[4] = {z2,z2,z2,z2}, rs23[4] = {z2,z2,z2,z2};
  f32x2 cs[4] = {z2,z2,z2,z2};
  #pragma unroll
  for (int mt=0;mt<4;mt++){
    #pragma unroll
    for (int nt=0;nt<4;nt++){
      f32x4 v = acc[mt][nt];
      float e0 = fexp2(v[0]), e1 = fexp2(v[1]);
      float e2 = fexp2(v[2]), e3 = fexp2(v[3]);
      f32x2 p01 = {e0,e1}, p23 = {e2,e3};
      rs01[mt] += p01; rs23[mt] += p23;
      cs[nt] += p01; cs[nt] += p23;
    }
  }
  #pragma unroll
  for (int mt=0;mt<4;mt++){
    union{f32x2 v; double d;} u0, u1;
    u0.v = rs01[mt]; u1.v = rs23[mt];
    #pragma unroll
    for (int m=1;m<16;m<<=1){
      union{double d; f32x2 v;} o0, o1;
      o0.d = __shfl_xor(u0.d, m); o1.d = __shfl_xor(u1.d, m);
      u0.v += o0.v; u1.v += o1.v;
    }
    if (cl==0){
      f32x4 rv = {u0.v.x, u0.v.y, u1.v.x, u1.v.y};
      *(f32x4*)&srow[wave][mt*16 + quad*4] = rv;
    }
  }
  __threadfence_block();
  P[((long)ti*256 + tj)*64 + lane] = srow[wave][lane];
  if (ti != tj){
    #pragma unroll
    for (int nt=0;nt<4;nt++){
      float s = cs[nt].x + cs[nt].y;
      s += __shfl_xor(s,16); s += __shfl_xor(s,32);
      if (quad==0) scol[wave][nt*16 + cl] = s;
    }
    __threadfence_block();
    P[((long)tj*256 + ti)*64 + lane] = scol[wave][lane];
  }
}

// ---- fused final reduce + loss: thread owns pair (i, i+8192), sums both P slices,
// computes log terms, block-reduce, atomicAdd into pre-zeroed d_out. ----
__global__ void rloss_k(const float* __restrict__ P, const float* __restrict__ bdot,
                        float* __restrict__ out){
  __shared__ float red[256];
  const float E2 = 7.3890560989306495f;  // exp(2) = diag(refl)
  int t = threadIdx.x;
  int i = blockIdx.x*256 + t;            // 0..8191
  int j = i + NROWS;
  const float* p1 = P + (long)(i>>6)*256*64 + (i&63);
  const float* p2 = P + (long)(j>>6)*256*64 + (j&63);
  float s1 = 0.f, s2 = 0.f;
  #pragma unroll 8
  for (int b=0;b<256;b++){ s1 += p1[b*64]; s2 += p2[b*64]; }
  float lb = 2.f * bdot[i];
  float term = 0.5f * ((logf(s1 - E2) - lb) + (logf(s2 - E2) - lb));
  red[t]=term; __syncthreads();
  for (int st=128; st>0; st>>=1){ if (t<st) red[t]+=red[t+st]; __syncthreads(); }
  if (t==0) atomicAdd(out, red[0] / (float)NROWS);
}

extern "C" void kernel_launch(void* const* d_in, const int* in_sizes, int n_in,
                              void* d_out, int out_size, void* d_ws, size_t ws_size,
                              hipStream_t stream){
  const float* feat1 = (const float*)d_in[0];
  const float* feat2 = (const float*)d_in[1];
  const int*   ei1   = (const int*)d_in[2];
  const float* w1    = (const float*)d_in[3];
  const int*   ei2   = (const int*)d_in[4];
  const float* w2    = (const float*)d_in[5];
  const float* w_l1a = (const float*)d_in[6];
  const float* b_l1a = (const float*)d_in[7];
  const float* w_l1b = (const float*)d_in[8];
  const float* b_l1b = (const float*)d_in[9];
  const float* w_g1  = (const float*)d_in[10];
  const float* b_g1  = (const float*)d_in[11];
  const float* w_g2  = (const float*)d_in[12];
  const float* b_g2  = (const float*)d_in[13];
  const float* w_fc1 = (const float*)d_in[14];
  const float* b_fc1 = (const float*)d_in[15];
  const float* w_fc2 = (const float*)d_in[16];
  const float* b_fc2 = (const float*)d_in[17];

  char* base = (char*)d_ws;
  size_t off = 0;
  auto alloc = [&](size_t bytes)->void*{
    void* r = base + off;
    off = (off + bytes + 255) & ~(size_t)255;
    return r;
  };
  // P (16MB) aliases [0,16MB): z, a1, xb, ax, head of hb — all dead before gram3_k.
  float* z    = (float*)alloc((size_t)MROWS*128*4);                 // [0,8M)
  short* a1   = (short*)alloc((size_t)MROWS*64*2);                  // [8M,10M)
  short* xb   = (short*)alloc((size_t)MROWS*32*2);                  // [10M,11M)
  short* ax   = (short*)alloc((size_t)MROWS*32*2);                  // [11M,12M)
  short* hb   = (short*)alloc((size_t)MROWS*256*2);                 // [12M,20M)
  short* s2   = (short*)alloc((size_t)MROWS*128*2);
  short* hh   = (short*)alloc((size_t)MROWS*128*2);
  short* t2   = (short*)alloc((size_t)MROWS*64*2);
  short* wl1a_t = (short*)alloc(512*64*2);
  short* wl1b_t = (short*)alloc(64*32*2);
  short* wg1_t  = (short*)alloc(32*256*2);
  short* wg2_t  = (short*)alloc(256*128*2);
  short* wfc1_t = (short*)alloc(128*64*2);
  short* wfc2_t = (short*)alloc(64*128*2);
  unsigned short* Zf = (unsigned short*)alloc((size_t)MROWS*128);   // fragment-order fp8 (2MB)
  int*   deg1 = (int*)alloc(NROWS*4);                               // zeroed pair
  int*   deg2 = (int*)alloc(NROWS*4);
  int* rs1  = (int*)alloc((NROWS+1)*4);
  int* cur1 = (int*)alloc(NROWS*4);
  int* rs2  = (int*)alloc((NROWS+1)*4);
  int* cur2 = (int*)alloc(NROWS*4);
  int*   ecol1 = (int*)alloc((size_t)NEDGE*4);
  float* ewt1  = (float*)alloc((size_t)NEDGE*4);
  int*   ecol2 = (int*)alloc((size_t)NEDGE*4);
  float* ewt2  = (float*)alloc((size_t)NEDGE*4);
  float* bdot  = (float*)alloc(NROWS*4);
  short* fb    = (short*)alloc((size_t)MROWS*512*2);                // bf16 feats (16MB)
  float* P = (float*)d_ws;   // 16MB alias (see note)

  hipMemsetAsync(deg1, 0, (size_t)2*NROWS*4, stream);
  hipMemsetAsync(d_out, 0, sizeof(float), stream);

  WtArgs wa;
  wa.src[0]=w_l1a; wa.dst[0]=wl1a_t; wa.K[0]=512; wa.N[0]=64;
  wa.src[1]=w_l1b; wa.dst[1]=wl1b_t; wa.K[1]=64;  wa.N[1]=32;
  wa.src[2]=w_g1;  wa.dst[2]=wg1_t;  wa.K[2]=32;  wa.N[2]=256;
  wa.src[3]=w_g2;  wa.dst[3]=wg2_t;  wa.K[3]=256; wa.N[3]=128;
  wa.src[4]=w_fc1; wa.dst[4]=wfc1_t; wa.K[4]=128; wa.N[4]=64;
  wa.src[5]=w_fc2; wa.dst[5]=wfc2_t; wa.K[5]=64;  wa.N[5]=128;
  wa.off[0]=0;
  for (int i=0;i<6;i++) wa.off[i+1] = wa.off[i] + wa.K[i]*wa.N[i];
  wa.nwt = (wa.off[6]+255)/256;
  const int ncvt = MROWS*512/4/256;   // 8192
  setup_k<<<wa.nwt + 2*(NEDGE/256) + ncvt,256,0,stream>>>(wa, ei1, ei2, deg1, deg2,
                                                          feat1, feat2, fb);
  scan2_k<<<2,256,0,stream>>>(deg1, rs1, cur1, deg2, rs2, cur2);
  fill2_k<<<2*(NEDGE/256),256,0,stream>>>(ei1, w1, cur1, ecol1, ewt1,
                                          ei2, w2, cur2, ecol2, ewt2);

  // encoder (both graphs batched: rows 0..8191 = view1, 8192..16383 = view2)
  gemm_k<64,512,1,true,false><<<MROWS/64,256,0,stream>>>(fb, wl1a_t, b_l1a, a1);
  gemm_k<32,64,0,true,false><<<MROWS/64,256,0,stream>>>(a1, wl1b_t, b_l1b, xb);
  // layer 1: aggregate FIRST in 32-dim space (adj@(x@W) == (adj@x)@W)
  gather_k<32,false,false><<<MROWS/64,256,0,stream>>>(xb, rs1,ecol1,ewt1, rs2,ecol2,ewt2, nullptr, ax);
  gemm_k<256,32,1,true,false><<<MROWS/64,256,0,stream>>>(ax, wg1_t, b_g1, hb);
  // layer 2: GEMM then aggregate (128 < 256 wide)
  gemm_k<128,256,0,false,false><<<MROWS/64,256,0,stream>>>(hb, wg2_t, nullptr, s2);
  gather_k<128,false,true><<<MROWS/16,256,0,stream>>>(s2, rs1,ecol1,ewt1, rs2,ecol2,ewt2, b_g2, hh);
  // projection
  gemm_k<64,128,2,true,false><<<MROWS/64,256,0,stream>>>(hh, wfc1_t, b_fc1, t2);
  gemm_k<128,64,0,true,true><<<MROWS/64,256,0,stream>>>(t2, wfc2_t, b_fc2, z);

  norm_k<<<NROWS/4,256,0,stream>>>(z, Zf, bdot);

  gram3_k<<<8224,256,0,stream>>>((const unsigned char*)Zf, P);   // 32896 UT tiles
  rloss_k<<<NROWS/256,256,0,stream>>>(P, bdot, (float*)d_out);
}

// Round 8
// 293.190 us; speedup vs baseline: 2.0783x; 2.0783x over previous
//
#include <hip/hip_runtime.h>
#include <hip/hip_bf16.h>
#include <math.h>

// GRACE-style graph contrastive loss, MI355X (gfx950).
// R8: revert gram3 launch_bounds (256,8)->(256,4). R7 post-mortem: the (256,8)
// floor capped the allocator at 32 VGPR -> acc/fragment spill to scratch ->
// 1.8GB HBM traffic, 55->360us. Keep R7's wins: sqrt(KE) input pre-scale
// (epilogue = raw v_exp_f32, no muls), feat fp32->bf16 in setup_k, fused rloss_k.

#define NROWS 8192
#define MROWS 16384
#define NEDGE 262144

typedef __attribute__((ext_vector_type(8))) short bf16x8;
typedef __attribute__((ext_vector_type(4))) float f32x4;
typedef __attribute__((ext_vector_type(2))) float f32x2;
typedef long long i64;

__device__ __forceinline__ short f2bf(float f){
  union { float f; unsigned u; } cv; cv.f = f;
  unsigned u = cv.u;
  unsigned r = (u + 0x7fffu + ((u >> 16) & 1u)) >> 16;  // RNE; inputs finite
  return (short)r;
}
__device__ __forceinline__ f32x4 mfma16(bf16x8 a, bf16x8 b, f32x4 c){
  return __builtin_amdgcn_mfma_f32_16x16x32_bf16(a, b, c, 0, 0, 0);
}
__device__ __forceinline__ float fexp2(float x){
#if __has_builtin(__builtin_amdgcn_exp2f)
  return __builtin_amdgcn_exp2f(x);   // raw v_exp_f32; args bounded |x|<3
#else
  return exp2f(x);
#endif
}

// ---- fp8 e4m3fn pack (RNE) ----
__device__ unsigned char f2e4m3_sw(float f){
  float a = fabsf(f);
  unsigned s = (__float_as_uint(f)>>24)&0x80u;
  if (!(a>0.f)) return (unsigned char)s;
  if (a>448.f) a=448.f;
  int e; frexpf(a,&e);
  int eff=e-1;
  unsigned code;
  if (eff<-6){
    float q=rintf(a*512.f);
    code=(unsigned)q; if(code>7)code=7;
  } else {
    float q=rintf(a*exp2f((float)(3-eff)));
    unsigned mant=(unsigned)q;
    if(mant>=16){mant=8;eff++;}
    if(eff>8) return (unsigned char)(s|0x7e);
    code=((unsigned)(eff+7)<<3)|(mant-8);
  }
  return (unsigned char)(s|code);
}
__device__ __forceinline__ unsigned short pack2fp8(float a, float b){
#if __has_builtin(__builtin_amdgcn_cvt_pk_fp8_f32)
  int v = __builtin_amdgcn_cvt_pk_fp8_f32(a, b, 0, false);
  return (unsigned short)(v & 0xffff);
#else
  return (unsigned short)((unsigned)f2e4m3_sw(a) | ((unsigned)f2e4m3_sw(b)<<8));
#endif
}

// ---- fused setup: weight transpose+bf16 | degree histogram | feat fp32->bf16 ----
struct WtArgs {
  const float* src[6];
  short* dst[6];
  int K[6], N[6];
  int off[7];
  int nwt;
};
__global__ void setup_k(WtArgs a, const int* __restrict__ ei1, const int* __restrict__ ei2,
                        int* __restrict__ deg1, int* __restrict__ deg2,
                        const float* __restrict__ feat1, const float* __restrict__ feat2,
                        short* __restrict__ fb){
  int b = blockIdx.x;
  if (b < a.nwt){
    int i = b*256 + threadIdx.x;
    if (i >= a.off[6]) return;
    int s = 0;
    #pragma unroll
    for (int j=1;j<6;j++) if (i >= a.off[j]) s=j;
    int l = i - a.off[s];
    int K=a.K[s], N=a.N[s];
    int k=l/N, n=l-k*N;
    a.dst[s][(long)n*K+k] = f2bf(a.src[s][l]);
  } else if (b < a.nwt + 2*(NEDGE/256)){
    int hb = b - a.nwt;
    const int* ei = (hb < NEDGE/256) ? ei1 : ei2;
    int* deg = (hb < NEDGE/256) ? deg1 : deg2;
    int e = (hb % (NEDGE/256))*256 + threadIdx.x;
    atomicAdd(&deg[ei[e]], 1);
  } else {
    // feat cvt: 8192 blocks, one float4 per thread over [feat1;feat2] -> fb bf16
    int idx = (b - a.nwt - 2*(NEDGE/256))*256 + threadIdx.x;   // float4 idx
    int row = idx >> 7, c4 = idx & 127;
    const float* src = (row < NROWS) ? (feat1 + (long)row*512 + c4*4)
                                     : (feat2 + (long)(row-NROWS)*512 + c4*4);
    float4 f = *(const float4*)src;
    uint2 o;
    o.x = (unsigned)(unsigned short)f2bf(f.x) | ((unsigned)(unsigned short)f2bf(f.y)<<16);
    o.y = (unsigned)(unsigned short)f2bf(f.z) | ((unsigned)(unsigned short)f2bf(f.w)<<16);
    *(uint2*)(fb + (long)row*512 + c4*4) = o;
  }
}

// ---- generic tall-skinny MFMA GEMM: Out[M,NN] = act(A[M,KK] @ Bt[NN,KK]^T + bias) ----
template<int NN, int KK, int ACT, bool BIAS, bool OUTF32>
__global__ __launch_bounds__(256) void gemm_k(const void* __restrict__ A0,
                                              const short* __restrict__ Bt, const float* __restrict__ bias,
                                              void* __restrict__ Out){
  constexpr int WM = (NN >= 64) ? 64 : 16;
  constexpr int WN = (NN >= 64) ? (NN/4) : NN;
  constexpr int MT = WM/16, NT = WN/16;
  const int tid = threadIdx.x;
  const int wave = tid >> 6, lane = tid & 63, quad = lane >> 4, cl = lane & 15;
  const int m0 = blockIdx.x * 64;
  const int wmo = (NN >= 64) ? 0 : wave*16;
  const int wno = (NN >= 64) ? wave*WN : 0;

  f32x4 zero = {0.f,0.f,0.f,0.f};
  f32x4 acc[MT][NT];
  #pragma unroll
  for (int i=0;i<MT;i++)
    #pragma unroll
    for (int j=0;j<NT;j++) acc[i][j] = zero;

  #pragma unroll
  for (int kc = 0; kc < KK/32; kc++){
    const int ko = kc*32 + quad*8;
    bf16x8 a[MT], b[NT];
    #pragma unroll
    for (int mt=0; mt<MT; mt++){
      int row = m0 + wmo + mt*16 + cl;
      a[mt] = *(const bf16x8*)((const short*)A0 + (long)row*KK + ko);
    }
    #pragma unroll
    for (int nt=0; nt<NT; nt++)
      b[nt] = *(const bf16x8*)(Bt + (long)(wno + nt*16 + cl)*KK + ko);
    #pragma unroll
    for (int mt=0; mt<MT; mt++)
      #pragma unroll
      for (int nt=0; nt<NT; nt++)
        acc[mt][nt] = mfma16(a[mt], b[nt], acc[mt][nt]);
  }
  #pragma unroll
  for (int mt=0; mt<MT; mt++){
    #pragma unroll
    for (int nt=0; nt<NT; nt++){
      int col = wno + nt*16 + cl;
      float bv = 0.f;
      if constexpr (BIAS) bv = bias[col];
      #pragma unroll
      for (int r=0;r<4;r++){
        int row = m0 + wmo + mt*16 + quad*4 + r;
        float v = acc[mt][nt][r] + bv;
        if (ACT==1) v = fmaxf(v, 0.f);
        if (ACT==2) v = (v > 0.f) ? v : expm1f(v);
        if constexpr (OUTF32) ((float*)Out)[(long)row*NN + col] = v;
        else ((short*)Out)[(long)row*NN + col] = f2bf(v);
      }
    }
  }
}

// ---- CSR build (both graphs fused per kernel) ----
__global__ void scan2_k(const int* __restrict__ deg1, int* __restrict__ rs1, int* __restrict__ cur1,
                        const int* __restrict__ deg2, int* __restrict__ rs2, int* __restrict__ cur2){
  const int* deg = blockIdx.x ? deg2 : deg1;
  int* rowstart = blockIdx.x ? rs2 : rs1;
  int* cursor = blockIdx.x ? cur2 : cur1;
  __shared__ int csum[256];
  __shared__ int base[257];
  int t = threadIdx.x;
  int loc[32];
  int s = 0;
  for (int j=0;j<32;j++){ int d = deg[t*32+j]; loc[j] = s; s += d; }
  csum[t] = s;
  __syncthreads();
  if (t==0){ int a=0; for (int i=0;i<256;i++){ base[i]=a; a+=csum[i]; } base[256]=a; }
  __syncthreads();
  for (int j=0;j<32;j++){ int v = base[t] + loc[j]; rowstart[t*32+j]=v; cursor[t*32+j]=v; }
  if (t==0) rowstart[NROWS] = base[256];
}
__global__ void fill2_k(const int* __restrict__ ei1, const float* __restrict__ w1, int* __restrict__ cur1,
                        int* __restrict__ ecol1, float* __restrict__ ew1,
                        const int* __restrict__ ei2, const float* __restrict__ w2, int* __restrict__ cur2,
                        int* __restrict__ ecol2, float* __restrict__ ew2){
  int b = blockIdx.x;
  bool g2 = (b >= NEDGE/256);
  const int* ei = g2 ? ei2 : ei1;
  const float* w = g2 ? w2 : w1;
  int* cursor = g2 ? cur2 : cur1;
  int* ecol = g2 ? ecol2 : ecol1;
  float* ew = g2 ? ew2 : ew1;
  int e = (b % (NEDGE/256))*256 + threadIdx.x;
  int r = ei[e];
  int p = atomicAdd(&cursor[r], 1);
  ecol[p] = ei[NEDGE + e];
  ew[p] = w[e];
}

// ---- GCN aggregation (gather form), latency-optimized: 8 gathers in flight ----
__device__ __forceinline__ void acc8(float* acc, int4 v, float f){
  const unsigned* u = (const unsigned*)&v;
  #pragma unroll
  for (int i=0;i<4;i++){
    union{unsigned x; float y;} lo, hi;
    lo.x = u[i] << 16;
    hi.x = u[i] & 0xffff0000u;
    acc[2*i]   = fmaf(f, lo.y, acc[2*i]);
    acc[2*i+1] = fmaf(f, hi.y, acc[2*i+1]);
  }
}

template<int C, bool RELU, bool HASB>
__global__ __launch_bounds__(256) void gather_k(const short* __restrict__ sup,
    const int* __restrict__ rs1, const int* __restrict__ ec1, const float* __restrict__ w1,
    const int* __restrict__ rs2, const int* __restrict__ ec2, const float* __restrict__ w2,
    const float* __restrict__ bias, short* __restrict__ out){
  constexpr int G = C/8;
  const int g = threadIdx.x % G;
  const int sub = threadIdx.x / G;
  const int row = blockIdx.x*(256/G) + sub;
  const int* rs; const int* ec; const float* w; int soff, lr;
  if (row < NROWS){ rs=rs1; ec=ec1; w=w1; soff=0; lr=row; }
  else            { rs=rs2; ec=ec2; w=w2; soff=NROWS; lr=row-NROWS; }
  const short* sb = sup + (long)soff*C + g*8;
  float acc[8];
  #pragma unroll
  for (int j=0;j<8;j++) acc[j] = HASB ? bias[g*8+j] : 0.f;
  const int s = rs[lr], e = rs[lr+1];
  int k = s;
  for (; k+8 <= e; k+=8){
    int c0=ec[k],c1=ec[k+1],c2=ec[k+2],c3=ec[k+3],c4=ec[k+4],c5=ec[k+5],c6=ec[k+6],c7=ec[k+7];
    float f0=w[k],f1=w[k+1],f2=w[k+2],f3=w[k+3],f4=w[k+4],f5=w[k+5],f6=w[k+6],f7=w[k+7];
    int4 v0 = *(const int4*)(sb + (long)c0*C);
    int4 v1 = *(const int4*)(sb + (long)c1*C);
    int4 v2 = *(const int4*)(sb + (long)c2*C);
    int4 v3 = *(const int4*)(sb + (long)c3*C);
    int4 v4 = *(const int4*)(sb + (long)c4*C);
    int4 v5 = *(const int4*)(sb + (long)c5*C);
    int4 v6 = *(const int4*)(sb + (long)c6*C);
    int4 v7 = *(const int4*)(sb + (long)c7*C);
    acc8(acc,v0,f0); acc8(acc,v1,f1); acc8(acc,v2,f2); acc8(acc,v3,f3);
    acc8(acc,v4,f4); acc8(acc,v5,f5); acc8(acc,v6,f6); acc8(acc,v7,f7);
  }
  for (; k+4 <= e; k+=4){
    int c0=ec[k],c1=ec[k+1],c2=ec[k+2],c3=ec[k+3];
    float f0=w[k],f1=w[k+1],f2=w[k+2],f3=w[k+3];
    int4 v0 = *(const int4*)(sb + (long)c0*C);
    int4 v1 = *(const int4*)(sb + (long)c1*C);
    int4 v2 = *(const int4*)(sb + (long)c2*C);
    int4 v3 = *(const int4*)(sb + (long)c3*C);
    acc8(acc,v0,f0); acc8(acc,v1,f1); acc8(acc,v2,f2); acc8(acc,v3,f3);
  }
  for (; k < e; k++){
    int c0=ec[k]; float f0=w[k];
    int4 v0 = *(const int4*)(sb + (long)c0*C);
    acc8(acc,v0,f0);
  }
  int4 ov;
  unsigned* ou = (unsigned*)&ov;
  #pragma unroll
  for (int i=0;i<4;i++){
    float a0 = acc[2*i], a1 = acc[2*i+1];
    if (RELU){ a0 = fmaxf(a0,0.f); a1 = fmaxf(a1,0.f); }
    unsigned p0 = (unsigned)(unsigned short)f2bf(a0);
    unsigned p1 = (unsigned)(unsigned short)f2bf(a1);
    ou[i] = p0 | (p1<<16);
  }
  *(int4*)(out + (long)row*C + g*8) = ov;
}

// ---- normalize rows of z (fp32 [16384,128]) -> fp8 * sqrt(KE) in MFMA fragment
// order (Zf); bdot[i] = z1n_i . z2n_i (fp32, unscaled). The sqrt(KE) pre-scale makes
// the Gram MFMA produce KE*(zi.zj) directly (bilinear), killing the epilogue mul.
__global__ __launch_bounds__(256) void norm_k(const float* __restrict__ z, unsigned short* __restrict__ Zf,
                                              float* __restrict__ bdot){
  const float SQKE = 1.6986436f;   // sqrt(2*log2(e))
  int wave = threadIdx.x>>6, lane = threadIdx.x&63;
  int i = blockIdx.x*4 + wave;   // row pair (i, i+8192)
  float2 a2 = *(const float2*)(z + (long)i*128 + lane*2);
  float2 b2 = *(const float2*)(z + (long)(i+NROWS)*128 + lane*2);
  float sa = a2.x*a2.x + a2.y*a2.y;
  float sb = b2.x*b2.x + b2.y*b2.y;
  #pragma unroll
  for (int m=1;m<64;m<<=1){ sa += __shfl_xor(sa,m); sb += __shfl_xor(sb,m); }
  float ra = 1.f / fmaxf(sqrtf(sa), 1e-12f);
  float rb = 1.f / fmaxf(sqrtf(sb), 1e-12f);
  float ras = ra*SQKE, rbs = rb*SQKE;
  const int d = lane>>1, kc = d>>3, q = (d>>1)&3, j4 = d&1, h = lane&1;
  const int base = kc*128 + j4;
  {
    int r = i;
    long o = ((long)(r>>4)*512 + base + ((r&15)+16*q)*2)*2 + h;
    Zf[o] = pack2fp8(a2.x*ras, a2.y*ras);
  }
  {
    int r = i + NROWS;
    long o = ((long)(r>>4)*512 + base + ((r&15)+16*q)*2)*2 + h;
    Zf[o] = pack2fp8(b2.x*rbs, b2.y*rbs);
  }
  float dd = (a2.x*ra)*(b2.x*rb) + (a2.y*ra)*(b2.y*rb);
  #pragma unroll
  for (int m=1;m<64;m<<=1) dd += __shfl_xor(dd,m);
  if (lane==0) bdot[i] = dd;
}

// ---- LDS-free symmetric exp-Gram partials. One 64x64 tile per WAVE over the upper
// triangle of the 256x256 tile grid. Inputs pre-scaled by sqrt(KE): epilogue is raw exp2.
// launch_bounds (256,4): DO NOT raise the wave floor — (256,8) capped VGPR at 32 and
// spilled acc/frags to scratch (R7: 1.8GB HBM traffic, 6.5x regression).
__global__ __launch_bounds__(256,4) void gram3_k(const unsigned char* __restrict__ Zf,
                                                 float* __restrict__ P){
  __shared__ float srow[4][64];
  __shared__ float scol[4][64];
  const int wave = threadIdx.x>>6, lane = threadIdx.x&63;
  const int t = blockIdx.x*4 + wave;           // UT tile index, T=256
  int ti = (int)((513.0f - sqrtf(513.0f*513.0f - 8.0f*(float)t))*0.5f);
  while ((ti+1)*256 - ((ti+1)*ti)/2 <= t) ti++;
  while (ti*256 - (ti*(ti-1))/2 > t) ti--;
  const int tj = ti + (t - (ti*256 - (ti*(ti-1))/2));
  const unsigned char* za = Zf + (long)ti*16*512 + lane*8;
  const unsigned char* zb = Zf + (long)tj*16*512 + lane*8;

  f32x4 zero = {0.f,0.f,0.f,0.f};
  f32x4 acc[4][4];
  #pragma unroll
  for (int i=0;i<4;i++)
    #pragma unroll
    for (int j=0;j<4;j++) acc[i][j]=zero;

  i64 aA[4], bA[4], aB[4], bB[4];
  #pragma unroll
  for (int x=0;x<4;x++){
    aA[x] = *(const i64*)(za + (x*4+0)*512);
    bA[x] = *(const i64*)(zb + (x*4+0)*512);
  }
  #pragma unroll
  for (int kc=0;kc<4;kc++){
    i64* ac = (kc&1) ? aB : aA;
    i64* bc = (kc&1) ? bB : bA;
    i64* an = (kc&1) ? aA : aB;
    i64* bn = (kc&1) ? bA : bB;
    if (kc<3){
      #pragma unroll
      for (int x=0;x<4;x++){
        an[x] = *(const i64*)(za + (x*4+kc+1)*512);
        bn[x] = *(const i64*)(zb + (x*4+kc+1)*512);
      }
    }
    #pragma unroll
    for (int mt=0;mt<4;mt++)
      #pragma unroll
      for (int nt=0;nt<4;nt++)
        acc[mt][nt] = __builtin_amdgcn_mfma_f32_16x16x32_fp8_fp8(ac[mt], bc[nt], acc[mt][nt], 0, 0, 0);
  }

  const int quad = lane>>4, cl = lane&15;
  f32x2 z2 = {0.f,0.f};
  f32x2 rs01[4] = {z2,z2,z2,z2}, rs23[4] = {z2,z2,z2,z2};
  f32x2 cs[4] = {z2,z2,z2,z2};
  #pragma unroll
  for (int mt=0;mt<4;mt++){
    #pragma unroll
    for (int nt=0;nt<4;nt++){
      f32x4 v = acc[mt][nt];
      float e0 = fexp2(v[0]), e1 = fexp2(v[1]);
      float e2 = fexp2(v[2]), e3 = fexp2(v[3]);
      f32x2 p01 = {e0,e1}, p23 = {e2,e3};
      rs01[mt] += p01; rs23[mt] += p23;
      cs[nt] += p01; cs[nt] += p23;
    }
  }
  #pragma unroll
  for (int mt=0;mt<4;mt++){
    union{f32x2 v; double d;} u0, u1;
    u0.v = rs01[mt]; u1.v = rs23[mt];
    #pragma unroll
    for (int m=1;m<16;m<<=1){
      union{double d; f32x2 v;} o0, o1;
      o0.d = __shfl_xor(u0.d, m); o1.d = __shfl_xor(u1.d, m);
      u0.v += o0.v; u1.v += o1.v;
    }
    if (cl==0){
      f32x4 rv = {u0.v.x, u0.v.y, u1.v.x, u1.v.y};
      *(f32x4*)&srow[wave][mt*16 + quad*4] = rv;
    }
  }
  __threadfence_block();
  P[((long)ti*256 + tj)*64 + lane] = srow[wave][lane];
  if (ti != tj){
    #pragma unroll
    for (int nt=0;nt<4;nt++){
      float s = cs[nt].x + cs[nt].y;
      s += __shfl_xor(s,16); s += __shfl_xor(s,32);
      if (quad==0) scol[wave][nt*16 + cl] = s;
    }
    __threadfence_block();
    P[((long)tj*256 + ti)*64 + lane] = scol[wave][lane];
  }
}

// ---- fused final reduce + loss: thread owns pair (i, i+8192), sums both P slices,
// computes log terms, block-reduce, atomicAdd into pre-zeroed d_out. ----
__global__ void rloss_k(const float* __restrict__ P, const float* __restrict__ bdot,
                        float* __restrict__ out){
  __shared__ float red[256];
  const float E2 = 7.3890560989306495f;  // exp(2) = diag(refl)
  int t = threadIdx.x;
  int i = blockIdx.x*256 + t;            // 0..8191
  int j = i + NROWS;
  const float* p1 = P + (long)(i>>6)*256*64 + (i&63);
  const float* p2 = P + (long)(j>>6)*256*64 + (j&63);
  float s1 = 0.f, s2 = 0.f;
  #pragma unroll 8
  for (int b=0;b<256;b++){ s1 += p1[b*64]; s2 += p2[b*64]; }
  float lb = 2.f * bdot[i];
  float term = 0.5f * ((logf(s1 - E2) - lb) + (logf(s2 - E2) - lb));
  red[t]=term; __syncthreads();
  for (int st=128; st>0; st>>=1){ if (t<st) red[t]+=red[t+st]; __syncthreads(); }
  if (t==0) atomicAdd(out, red[0] / (float)NROWS);
}

extern "C" void kernel_launch(void* const* d_in, const int* in_sizes, int n_in,
                              void* d_out, int out_size, void* d_ws, size_t ws_size,
                              hipStream_t stream){
  const float* feat1 = (const float*)d_in[0];
  const float* feat2 = (const float*)d_in[1];
  const int*   ei1   = (const int*)d_in[2];
  const float* w1    = (const float*)d_in[3];
  const int*   ei2   = (const int*)d_in[4];
  const float* w2    = (const float*)d_in[5];
  const float* w_l1a = (const float*)d_in[6];
  const float* b_l1a = (const float*)d_in[7];
  const float* w_l1b = (const float*)d_in[8];
  const float* b_l1b = (const float*)d_in[9];
  const float* w_g1  = (const float*)d_in[10];
  const float* b_g1  = (const float*)d_in[11];
  const float* w_g2  = (const float*)d_in[12];
  const float* b_g2  = (const float*)d_in[13];
  const float* w_fc1 = (const float*)d_in[14];
  const float* b_fc1 = (const float*)d_in[15];
  const float* w_fc2 = (const float*)d_in[16];
  const float* b_fc2 = (const float*)d_in[17];

  char* base = (char*)d_ws;
  size_t off = 0;
  auto alloc = [&](size_t bytes)->void*{
    void* r = base + off;
    off = (off + bytes + 255) & ~(size_t)255;
    return r;
  };
  // P (16MB) aliases [0,16MB): z, a1, xb, ax, head of hb — all dead before gram3_k.
  float* z    = (float*)alloc((size_t)MROWS*128*4);                 // [0,8M)
  short* a1   = (short*)alloc((size_t)MROWS*64*2);                  // [8M,10M)
  short* xb   = (short*)alloc((size_t)MROWS*32*2);                  // [10M,11M)
  short* ax   = (short*)alloc((size_t)MROWS*32*2);                  // [11M,12M)
  short* hb   = (short*)alloc((size_t)MROWS*256*2);                 // [12M,20M)
  short* s2   = (short*)alloc((size_t)MROWS*128*2);
  short* hh   = (short*)alloc((size_t)MROWS*128*2);
  short* t2   = (short*)alloc((size_t)MROWS*64*2);
  short* wl1a_t = (short*)alloc(512*64*2);
  short* wl1b_t = (short*)alloc(64*32*2);
  short* wg1_t  = (short*)alloc(32*256*2);
  short* wg2_t  = (short*)alloc(256*128*2);
  short* wfc1_t = (short*)alloc(128*64*2);
  short* wfc2_t = (short*)alloc(64*128*2);
  unsigned short* Zf = (unsigned short*)alloc((size_t)MROWS*128);   // fragment-order fp8 (2MB)
  int*   deg1 = (int*)alloc(NROWS*4);                               // zeroed pair
  int*   deg2 = (int*)alloc(NROWS*4);
  int* rs1  = (int*)alloc((NROWS+1)*4);
  int* cur1 = (int*)alloc(NROWS*4);
  int* rs2  = (int*)alloc((NROWS+1)*4);
  int* cur2 = (int*)alloc(NROWS*4);
  int*   ecol1 = (int*)alloc((size_t)NEDGE*4);
  float* ewt1  = (float*)alloc((size_t)NEDGE*4);
  int*   ecol2 = (int*)alloc((size_t)NEDGE*4);
  float* ewt2  = (float*)alloc((size_t)NEDGE*4);
  float* bdot  = (float*)alloc(NROWS*4);
  short* fb    = (short*)alloc((size_t)MROWS*512*2);                // bf16 feats (16MB)
  float* P = (float*)d_ws;   // 16MB alias (see note)

  hipMemsetAsync(deg1, 0, (size_t)2*NROWS*4, stream);
  hipMemsetAsync(d_out, 0, sizeof(float), stream);

  WtArgs wa;
  wa.src[0]=w_l1a; wa.dst[0]=wl1a_t; wa.K[0]=512; wa.N[0]=64;
  wa.src[1]=w_l1b; wa.dst[1]=wl1b_t; wa.K[1]=64;  wa.N[1]=32;
  wa.src[2]=w_g1;  wa.dst[2]=wg1_t;  wa.K[2]=32;  wa.N[2]=256;
  wa.src[3]=w_g2;  wa.dst[3]=wg2_t;  wa.K[3]=256; wa.N[3]=128;
  wa.src[4]=w_fc1; wa.dst[4]=wfc1_t; wa.K[4]=128; wa.N[4]=64;
  wa.src[5]=w_fc2; wa.dst[5]=wfc2_t; wa.K[5]=64;  wa.N[5]=128;
  wa.off[0]=0;
  for (int i=0;i<6;i++) wa.off[i+1] = wa.off[i] + wa.K[i]*wa.N[i];
  wa.nwt = (wa.off[6]+255)/256;
  const int ncvt = MROWS*512/4/256;   // 8192
  setup_k<<<wa.nwt + 2*(NEDGE/256) + ncvt,256,0,stream>>>(wa, ei1, ei2, deg1, deg2,
                                                          feat1, feat2, fb);
  scan2_k<<<2,256,0,stream>>>(deg1, rs1, cur1, deg2, rs2, cur2);
  fill2_k<<<2*(NEDGE/256),256,0,stream>>>(ei1, w1, cur1, ecol1, ewt1,
                                          ei2, w2, cur2, ecol2, ewt2);

  // encoder (both graphs batched: rows 0..8191 = view1, 8192..16383 = view2)
  gemm_k<64,512,1,true,false><<<MROWS/64,256,0,stream>>>(fb, wl1a_t, b_l1a, a1);
  gemm_k<32,64,0,true,false><<<MROWS/64,256,0,stream>>>(a1, wl1b_t, b_l1b, xb);
  // layer 1: aggregate FIRST in 32-dim space (adj@(x@W) == (adj@x)@W)
  gather_k<32,false,false><<<MROWS/64,256,0,stream>>>(xb, rs1,ecol1,ewt1, rs2,ecol2,ewt2, nullptr, ax);
  gemm_k<256,32,1,true,false><<<MROWS/64,256,0,stream>>>(ax, wg1_t, b_g1, hb);
  // layer 2: GEMM then aggregate (128 < 256 wide)
  gemm_k<128,256,0,false,false><<<MROWS/64,256,0,stream>>>(hb, wg2_t, nullptr, s2);
  gather_k<128,false,true><<<MROWS/16,256,0,stream>>>(s2, rs1,ecol1,ewt1, rs2,ecol2,ewt2, b_g2, hh);
  // projection
  gemm_k<64,128,2,true,false><<<MROWS/64,256,0,stream>>>(hh, wfc1_t, b_fc1, t2);
  gemm_k<128,64,0,true,true><<<MROWS/64,256,0,stream>>>(t2, wfc2_t, b_fc2, z);

  norm_k<<<NROWS/4,256,0,stream>>>(z, Zf, bdot);

  gram3_k<<<8224,256,0,stream>>>((const unsigned char*)Zf, P);   // 32896 UT tiles
  rloss_k<<<NROWS/256,256,0,stream>>>(P, bdot, (float*)d_out);
}